// Round 3
// baseline (771.311 us; speedup 1.0000x reference)
//
#include <hip/hip_runtime.h>
#include <cstdint>
#include <cstddef>

// CTC-CRF logZ forward: S=1024 states, NZ=5.
// alpha'[s] = LSE(m0+alpha[s], m1+alpha[p], m2+alpha[256+p], m3+alpha[512+p], m4+alpha[768+p]),
//   p = s>>2, m_j = scores[t][n][s*5+j].
// One block per batch element (32 blocks, 1024 threads, 1 state/thread).
// Scores global->VGPR directly (no cross-thread sharing): dwordx4+dword per
// thread per step, software-pipelined DEPTH-7 with 8 named register sets
// (static indexing only) and one running pointer per set (no per-step mul).
// Only alpha lives in LDS, permuted ap[p*4+b]=alpha[256b+p] -> one
// conflict-free ds_read_b128 per thread. Raw s_barrier + lgkmcnt(0) only:
// prefetch loads stay in flight across barriers; the compiler inserts
// counted vmcnt(N) before each set's first use.

#define NB 32
#define SD 1024
#define CD 5120

typedef float f4a __attribute__((ext_vector_type(4), aligned(4)));

__device__ __forceinline__ float fexp2(float x) { return __builtin_amdgcn_exp2f(x); }
__device__ __forceinline__ float flog2(float x) { return __builtin_amdgcn_logf(x); }

__global__ void __launch_bounds__(1024) ctc_logz(const float* __restrict__ scores,
                                                 float* __restrict__ out, int T) {
  __shared__ float ap[2 * SD];   // permuted alpha, double-buffered
  __shared__ float red[32];

  const int tid = threadIdx.x;
  const int n = blockIdx.x;
  const int lane = tid & 63;
  const int wid = tid >> 6;
  const int p4 = (tid >> 2) << 2;                   // predecessor chunk base
  const int awr = ((tid & 255) << 2) | (tid >> 8);  // ap slot: p*4 + b

  ap[tid] = 0.f;
  ap[SD + tid] = 0.f;
  float a_cur = 0.f;

  const float K = 1.44269504088896340736f;    // log2(e)
  const float LN2 = 0.69314718055994530942f;  // ln(2)

  const float* sn = scores + (size_t)n * CD + (size_t)tid * 5;
  const size_t tstr = (size_t)NB * CD;   // elements per timestep
  const size_t str8 = 8 * tstr;

  auto CP = [&](int t, const f4a& qa, float qb) {
    const f4a av = *(const f4a*)&ap[((t + 1) & 1) * SD + p4];  // ds_read_b128
    float t0 = qa.x + a_cur;   // stay
    float t1 = qa.y + av.x;    // alpha[p]
    float t2 = qa.z + av.y;    // alpha[256+p]
    float t3 = qa.w + av.z;    // alpha[512+p]
    float t4 = qb + av.w;      // alpha[768+p]
    float mx = fmaxf(t4, fmaxf(fmaxf(t0, t1), fmaxf(t2, t3)));
    float nk = -mx * K;
    float s = fexp2(__builtin_fmaf(t0, K, nk));
    s += fexp2(__builtin_fmaf(t1, K, nk));
    s += fexp2(__builtin_fmaf(t2, K, nk));
    s += fexp2(__builtin_fmaf(t3, K, nk));
    s += fexp2(__builtin_fmaf(t4, K, nk));
    a_cur = __builtin_fmaf(flog2(s), LN2, mx);
    ap[(t & 1) * SD + awr] = a_cur;
    // drain only LDS before the barrier; global prefetches stay in flight.
    asm volatile("s_waitcnt lgkmcnt(0)\n\ts_barrier" ::: "memory");
  };

  // 8 register sets + 8 running pointers. Prologue: clamped issue of t=0..7.
#define PRO(c)                                                              \
  const float* P##c = sn + (size_t)((c) < T ? (c) : T - 1) * tstr;          \
  f4a qa##c = *(const f4a*)P##c;                                            \
  float qb##c = P##c[4];                                                    \
  P##c += str8;
  PRO(0) PRO(1) PRO(2) PRO(3) PRO(4) PRO(5) PRO(6) PRO(7)
#undef PRO

  __syncthreads();  // ap zeros visible

  // reload set c (time t+8+c), advance pointer
#define RL(c)                                                               \
  qa##c = *(const f4a*)P##c;                                                \
  qb##c = P##c[4];                                                          \
  P##c += str8;

  int t = 0;
  for (; t + 16 <= T; t += 8) {
    CP(t + 0, qa0, qb0); RL(0)
    CP(t + 1, qa1, qb1); RL(1)
    CP(t + 2, qa2, qb2); RL(2)
    CP(t + 3, qa3, qb3); RL(3)
    CP(t + 4, qa4, qb4); RL(4)
    CP(t + 5, qa5, qb5); RL(5)
    CP(t + 6, qa6, qb6); RL(6)
    CP(t + 7, qa7, qb7); RL(7)
  }
#undef RL

  // epilogue phase 1: consume resident sets t..t+7, top up loads where valid
#define EPI1(c)                                                             \
  if (t + (c) < T) {                                                        \
    CP(t + (c), qa##c, qb##c);                                              \
    if (t + 8 + (c) < T) { qa##c = *(const f4a*)P##c; qb##c = P##c[4]; }    \
  }
  EPI1(0) EPI1(1) EPI1(2) EPI1(3) EPI1(4) EPI1(5) EPI1(6) EPI1(7)
#undef EPI1
  t += 8;
  // epilogue phase 2: consume the remainder
#define EPI2(c) if (t + (c) < T) CP(t + (c), qa##c, qb##c);
  EPI2(0) EPI2(1) EPI2(2) EPI2(3) EPI2(4) EPI2(5) EPI2(6) EPI2(7)
#undef EPI2

  // logZ[n] = LSE over all 1024 alpha (vT = 0)
  float m = a_cur;
#pragma unroll
  for (int d = 1; d < 64; d <<= 1) m = fmaxf(m, __shfl_xor(m, d, 64));
  if (lane == 0) red[wid] = m;
  __syncthreads();
  float bm = red[0];
#pragma unroll
  for (int i = 1; i < 16; ++i) bm = fmaxf(bm, red[i]);
  float e = fexp2((a_cur - bm) * K);
#pragma unroll
  for (int d = 1; d < 64; d <<= 1) e += __shfl_xor(e, d, 64);
  if (lane == 0) red[16 + wid] = e;
  __syncthreads();
  if (tid == 0) {
    float ssum = red[16];
#pragma unroll
    for (int i = 1; i < 16; ++i) ssum += red[16 + i];
    out[n] = __builtin_fmaf(flog2(ssum), LN2, bm);
  }
}

extern "C" void kernel_launch(void* const* d_in, const int* in_sizes, int n_in,
                              void* d_out, int out_size, void* d_ws, size_t ws_size,
                              hipStream_t stream) {
  const float* scores = (const float*)d_in[0];
  float* out = (float*)d_out;
  const long long tot = (long long)in_sizes[0];
  const int T = (int)(tot / ((long long)NB * CD));
  ctc_logz<<<dim3(NB), dim3(1024), 0, stream>>>(scores, out, T);
}

// Round 4
// 761.791 us; speedup vs baseline: 1.0125x; 1.0125x over previous
//
#include <hip/hip_runtime.h>
#include <cstdint>
#include <cstddef>

// CTC-CRF logZ forward: S=1024 states, NZ=5.
// Linear-domain recursion with lagged power-of-2 renormalization:
//   A[t][s] = 2^(K*alpha[t][s] - C_t),  K = log2(e)
//   A'[s]   = sum_j 2^(K*m_j - e_t) * A[pred_j],   C_{t+1} = C_t + e_t
// e_t = biased-exponent of broadcast ref value A[t][state0] (uniform-address
// LDS read -> broadcast; integer bfe -> exact renorm, no log/max per state).
// One block per batch element (32 blocks, 1024 threads, 1 state/thread).
// Scores global->VGPR (dwordx4+dword), depth-8 rotating register pipeline
// (statically indexed, running pointer per set). Alpha in LDS, permuted
// ap[p*4+b] = A[256b+p] -> one conflict-free ds_read_b128 for 4 preds.
// Raw s_barrier + lgkmcnt(0) only: prefetches stay in flight across barriers.

#define NB 32
#define SD 1024
#define CD 5120

typedef float f4a __attribute__((ext_vector_type(4), aligned(4)));

__device__ __forceinline__ float fexp2(float x) { return __builtin_amdgcn_exp2f(x); }
__device__ __forceinline__ float flog2(float x) { return __builtin_amdgcn_logf(x); }

__global__ void __launch_bounds__(1024) ctc_logz(const float* __restrict__ scores,
                                                 float* __restrict__ out, int T) {
  __shared__ float ap[2 * SD];   // permuted A, double-buffered
  __shared__ float red[16];

  const int tid = threadIdx.x;
  const int n = blockIdx.x;
  const int lane = tid & 63;
  const int wid = tid >> 6;
  const int p4 = (tid >> 2) << 2;                   // predecessor chunk base
  const int awr = ((tid & 255) << 2) | (tid >> 8);  // ap slot: p*4 + b

  ap[tid] = 1.f;        // A = 2^(K*0 - 0) = 1
  ap[SD + tid] = 1.f;
  float a_cur = 1.f;
  int cacc = 0;         // sum of biased exponents (subtract 127*T at end)

  const float K = 1.44269504088896340736f;    // log2(e)
  const float LN2 = 0.69314718055994530942f;  // ln(2)

  const float* sn = scores + (size_t)n * CD + (size_t)tid * 5;
  const size_t tstr = (size_t)NB * CD;   // elements per timestep
  const size_t str8 = 8 * tstr;

  auto CP = [&](int t, const f4a& qa, float qb) {
    const int rbuf = ((t + 1) & 1) * SD;
    const f4a av = *(const f4a*)&ap[rbuf + p4];  // ds_read_b128 (4 preds)
    const float R = ap[rbuf];                    // uniform addr -> broadcast
    const int xb = (__float_as_int(R) >> 23) & 0xFF;  // biased exponent
    cacc += xb;
    const float nLf = (float)(127 - xb);         // -e_t
    float e0 = fexp2(__builtin_fmaf(qa.x, K, nLf));
    float e1 = fexp2(__builtin_fmaf(qa.y, K, nLf));
    float e2 = fexp2(__builtin_fmaf(qa.z, K, nLf));
    float e3 = fexp2(__builtin_fmaf(qa.w, K, nLf));
    float e4 = fexp2(__builtin_fmaf(qb,   K, nLf));
    float s = e0 * a_cur;                        // stay
    s = __builtin_fmaf(e1, av.x, s);
    s = __builtin_fmaf(e2, av.y, s);
    s = __builtin_fmaf(e3, av.z, s);
    s = __builtin_fmaf(e4, av.w, s);
    a_cur = s;
    ap[(t & 1) * SD + awr] = s;
    // drain only LDS before the barrier; global prefetches stay in flight.
    asm volatile("s_waitcnt lgkmcnt(0)\n\ts_barrier" ::: "memory");
  };

  // 8 register sets + 8 running pointers. Prologue: clamped issue of t=0..7.
#define PRO(c)                                                              \
  const float* P##c = sn + (size_t)((c) < T ? (c) : T - 1) * tstr;          \
  f4a qa##c = *(const f4a*)P##c;                                            \
  float qb##c = P##c[4];                                                    \
  P##c += str8;
  PRO(0) PRO(1) PRO(2) PRO(3) PRO(4) PRO(5) PRO(6) PRO(7)
#undef PRO

  __syncthreads();  // ap init visible

#define RL(c)                                                               \
  qa##c = *(const f4a*)P##c;                                                \
  qb##c = P##c[4];                                                          \
  P##c += str8;

  int t = 0;
  for (; t + 16 <= T; t += 8) {
    CP(t + 0, qa0, qb0); RL(0)
    CP(t + 1, qa1, qb1); RL(1)
    CP(t + 2, qa2, qb2); RL(2)
    CP(t + 3, qa3, qb3); RL(3)
    CP(t + 4, qa4, qb4); RL(4)
    CP(t + 5, qa5, qb5); RL(5)
    CP(t + 6, qa6, qb6); RL(6)
    CP(t + 7, qa7, qb7); RL(7)
  }
#undef RL

#define EPI1(c)                                                             \
  if (t + (c) < T) {                                                        \
    CP(t + (c), qa##c, qb##c);                                              \
    if (t + 8 + (c) < T) { qa##c = *(const f4a*)P##c; qb##c = P##c[4]; }    \
  }
  EPI1(0) EPI1(1) EPI1(2) EPI1(3) EPI1(4) EPI1(5) EPI1(6) EPI1(7)
#undef EPI1
  t += 8;
#define EPI2(c) if (t + (c) < T) CP(t + (c), qa##c, qb##c);
  EPI2(0) EPI2(1) EPI2(2) EPI2(3) EPI2(4) EPI2(5) EPI2(6) EPI2(7)
#undef EPI2

  // logZ[n] = ln2 * (C_T + log2(sum_s A_T[s])),  C_T = cacc - 127*T
  float v = a_cur;
#pragma unroll
  for (int d = 1; d < 64; d <<= 1) v += __shfl_xor(v, d, 64);
  if (lane == 0) red[wid] = v;
  __syncthreads();
  if (tid == 0) {
    float ssum = red[0];
#pragma unroll
    for (int i = 1; i < 16; ++i) ssum += red[i];
    out[n] = LN2 * ((float)(cacc - 127 * T) + flog2(ssum));
  }
}

extern "C" void kernel_launch(void* const* d_in, const int* in_sizes, int n_in,
                              void* d_out, int out_size, void* d_ws, size_t ws_size,
                              hipStream_t stream) {
  const float* scores = (const float*)d_in[0];
  float* out = (float*)d_out;
  const long long tot = (long long)in_sizes[0];
  const int T = (int)(tot / ((long long)NB * CD));
  ctc_logz<<<dim3(NB), dim3(1024), 0, stream>>>(scores, out, T);
}